// Round 4
// baseline (1342.889 us; speedup 1.0000x reference)
//
#include <hip/hip_runtime.h>
#include <math.h>

#define N_TOK  131072
#define DIM    1024
#define HIDN   256
#define ATTN   128
#define NSEG   64
#define SEGLEN 2048
#define NCLS   2
#define EPSLN  1e-5f

typedef __attribute__((ext_vector_type(8))) short  short8;
typedef __attribute__((ext_vector_type(4))) float  f32x4;

__device__ __forceinline__ unsigned short f2bf(float f) {
    unsigned int u = __float_as_uint(f);
    u += 0x7fffu + ((u >> 16) & 1u);
    return (unsigned short)(u >> 16);
}
__device__ __forceinline__ float bf2f(unsigned short h) {
    return __uint_as_float(((unsigned int)h) << 16);
}
__device__ __forceinline__ float gelu_exact(float x) {
    return 0.5f * x * (1.0f + erff(x * 0.70710678118654752f));
}

// One kernel for ALL weight prep: 385 blocks of 32x8 threads.
//  blocks 0..255  : W1  (1024x256) -> W1t  [256][1024]
//  blocks 256..319: W2  (256x256)  -> W2t  [256][256]
//  blocks 320..351: Wv  (256x128)  -> Wvut rows 0..127
//  blocks 352..383: Wu  (256x128)  -> Wvut rows 128..255
//  block  384     : bvu = [bv | bu]
__global__ __launch_bounds__(256) void prep_weights(const float* __restrict__ W1,
                                                    const float* __restrict__ W2,
                                                    const float* __restrict__ Wv,
                                                    const float* __restrict__ Wu,
                                                    const float* __restrict__ bv,
                                                    const float* __restrict__ bu,
                                                    unsigned short* __restrict__ W1t,
                                                    unsigned short* __restrict__ W2t,
                                                    unsigned short* __restrict__ Wvut,
                                                    float* __restrict__ bvu) {
    const int b = blockIdx.x;
    const int x = threadIdx.x, y = threadIdx.y;  // 32 x 8
    if (b == 384) {
        const int t = y * 32 + x;
        bvu[t] = (t < 128) ? bv[t] : bu[t - 128];
        return;
    }
    const float* in; unsigned short* out; int R, C, tx, ty;
    if (b < 256)      { in = W1; out = W1t;                        R = DIM;  C = HIDN; tx = b & 7;         ty = b >> 3; }
    else if (b < 320) { in = W2; out = W2t;                        R = HIDN; C = HIDN; tx = (b - 256) & 7; ty = (b - 256) >> 3; }
    else if (b < 352) { in = Wv; out = Wvut;                       R = HIDN; C = ATTN; tx = (b - 320) & 3; ty = (b - 320) >> 2; }
    else              { in = Wu; out = Wvut + (size_t)ATTN * HIDN; R = HIDN; C = ATTN; tx = (b - 352) & 3; ty = (b - 352) >> 2; }
    __shared__ float t[32][33];
    const int bx = tx * 32, by = ty * 32;
#pragma unroll
    for (int i = 0; i < 32; i += 8) t[y + i][x] = in[(size_t)(by + y + i) * C + bx + x];
    __syncthreads();
#pragma unroll
    for (int i = 0; i < 32; i += 8) out[(size_t)(bx + y + i) * R + by + x] = f2bf(t[x][y + i]);
}

// Mega-fused: per 64-row block: h1=gelu(ln(x@W1+b1)); h2=gelu(ln(h1@W2+b2)) -> h2b global;
// score row = sum_j tanh(v_j)*sigmoid(u_j)*Ww_j + bw where [v|u] = h2@Wvut^T + bvu.
// Phase 1: x staged via LDS (As) + W1 staged via LDS (Ws), 2 barriers/K-step (proven structure).
// Phases 2/3: A read directly from the resident h-tile in LDS; B fragments loaded lane-direct
// from L2 (weights are 128 KB, hot in every XCD's L2) -> ZERO barriers inside the K-loops.
// LDS map (35840 B total):
//   [0      .. 33792) h-tile [64][264] ushort;  phase-1 staging As[64][40]+Ws[256][40] (25600 B)
//                     and epilogue-3 us[64][129] f32 (33024 B) alias this region (phase-disjoint).
//   [33792  .. 35840) red [2][4][64] f32 (LN sums);  ep3 pw[2][64] aliases it.
__global__ __launch_bounds__(256, 3) void fused_mlp_score(
    const float* __restrict__ x,
    const unsigned short* __restrict__ W1t,
    const unsigned short* __restrict__ W2t,
    const unsigned short* __restrict__ Wvut,
    const float* __restrict__ b1, const float* __restrict__ g1, const float* __restrict__ be1,
    const float* __restrict__ b2, const float* __restrict__ g2, const float* __restrict__ be2,
    const float* __restrict__ bvu, const float* __restrict__ Ww, const float* __restrict__ bw,
    unsigned short* __restrict__ h2b, float* __restrict__ scores) {
    __shared__ __align__(16) char smem[35840];
    auto As  = (unsigned short (*)[40])smem;
    auto Ws  = (unsigned short (*)[40])(smem + 5120);
    auto HT  = (unsigned short (*)[264])smem;
    auto red = (float (*)[4][64])(smem + 33792);   // [2][4][64]

    const int tid  = threadIdx.x;
    const int wave = tid >> 6, lane = tid & 63;
    const int lr = lane & 15, lq = lane >> 4;
    const int srow = tid >> 2, skq = (tid & 3) * 8;
    const size_t row0 = (size_t)blockIdx.x * 64;

    f32x4 acc[4][4];
    auto zero_acc = [&]() {
#pragma unroll
        for (int i = 0; i < 4; i++)
#pragma unroll
            for (int j = 0; j < 4; j++) acc[i][j] = (f32x4)0.0f;
    };

    // LN + GELU epilogue over acc; writes bf16 into HT, optionally also to global h2b.
    auto ln_epilogue = [&](const float* bias, const float* gamma, const float* beta, bool toGlobal) {
        float bjv[4];
#pragma unroll
        for (int j = 0; j < 4; j++) bjv[j] = bias[wave * 64 + 16 * j + lr];
#pragma unroll
        for (int i = 0; i < 4; i++)
#pragma unroll
            for (int j = 0; j < 4; j++)
#pragma unroll
                for (int r = 0; r < 4; r++) acc[i][j][r] += bjv[j];
#pragma unroll
        for (int i = 0; i < 4; i++)
#pragma unroll
            for (int r = 0; r < 4; r++) {
                float s = 0.0f, sq = 0.0f;
#pragma unroll
                for (int j = 0; j < 4; j++) { float v = acc[i][j][r]; s += v; sq += v * v; }
#pragma unroll
                for (int m = 1; m < 16; m <<= 1) { s += __shfl_xor(s, m); sq += __shfl_xor(sq, m); }
                if (lr == 0) {
                    red[0][wave][16 * i + 4 * lq + r] = s;
                    red[1][wave][16 * i + 4 * lq + r] = sq;
                }
            }
        __syncthreads();
        float gj[4], bej[4];
#pragma unroll
        for (int j = 0; j < 4; j++) {
            gj[j]  = gamma[wave * 64 + 16 * j + lr];
            bej[j] = beta[wave * 64 + 16 * j + lr];
        }
#pragma unroll
        for (int i = 0; i < 4; i++)
#pragma unroll
            for (int r = 0; r < 4; r++) {
                const int row = 16 * i + 4 * lq + r;
                const float s  = red[0][0][row] + red[0][1][row] + red[0][2][row] + red[0][3][row];
                const float sq = red[1][0][row] + red[1][1][row] + red[1][2][row] + red[1][3][row];
                const float mu  = s * (1.0f / HIDN);
                const float var = sq * (1.0f / HIDN) - mu * mu;
                const float rs  = rsqrtf(var + EPSLN);
#pragma unroll
                for (int j = 0; j < 4; j++) {
                    const int col = wave * 64 + 16 * j + lr;
                    const unsigned short hv = f2bf(gelu_exact((acc[i][j][r] - mu) * rs * gj[j] + bej[j]));
                    HT[row][col] = hv;
                    if (toGlobal) h2b[(row0 + row) * 256 + col] = hv;
                }
            }
        __syncthreads();   // h-tile fully written before next phase reads it
    };

    // ---------------- phase 1: x @ W1t^T (K=1024, LDS-staged) ----------------
    zero_acc();
    for (int k0 = 0; k0 < DIM; k0 += 32) {
        const float* p = &x[(row0 + srow) * DIM + k0 + skq];
        float4 v0 = *(const float4*)p;
        float4 v1 = *(const float4*)(p + 4);
        short8 aw;
        aw[0] = (short)f2bf(v0.x); aw[1] = (short)f2bf(v0.y);
        aw[2] = (short)f2bf(v0.z); aw[3] = (short)f2bf(v0.w);
        aw[4] = (short)f2bf(v1.x); aw[5] = (short)f2bf(v1.y);
        aw[6] = (short)f2bf(v1.z); aw[7] = (short)f2bf(v1.w);
        short8 ww[4];
#pragma unroll
        for (int c = 0; c < 4; c++)
            ww[c] = *(const short8*)&W1t[(size_t)(srow + 64 * c) * DIM + k0 + skq];
        __syncthreads();   // previous tile fully consumed
        *(short8*)&As[srow][skq] = aw;
#pragma unroll
        for (int c = 0; c < 4; c++)
            *(short8*)&Ws[srow + 64 * c][skq] = ww[c];
        __syncthreads();
        short8 a[4], b[4];
#pragma unroll
        for (int i = 0; i < 4; i++) a[i] = *(const short8*)&As[16 * i + lr][lq * 8];
#pragma unroll
        for (int j = 0; j < 4; j++) b[j] = *(const short8*)&Ws[64 * wave + 16 * j + lr][lq * 8];
#pragma unroll
        for (int i = 0; i < 4; i++)
#pragma unroll
            for (int j = 0; j < 4; j++)
                acc[i][j] = __builtin_amdgcn_mfma_f32_16x16x32_bf16(a[i], b[j], acc[i][j], 0, 0, 0);
    }
    __syncthreads();   // staging LDS dead -> h-tile region writable
    ln_epilogue(b1, g1, be1, false);

    // ---------------- phase 2: h1 @ W2t^T (K=256, barrier-free) ----------------
    zero_acc();
#pragma unroll 2
    for (int t = 0; t < 8; t++) {
        const int k0 = t * 32;
        short8 a[4], b[4];
#pragma unroll
        for (int j = 0; j < 4; j++)
            b[j] = *(const short8*)&W2t[(size_t)(64 * wave + 16 * j + lr) * HIDN + k0 + lq * 8];
#pragma unroll
        for (int i = 0; i < 4; i++) a[i] = *(const short8*)&HT[16 * i + lr][k0 + lq * 8];
#pragma unroll
        for (int i = 0; i < 4; i++)
#pragma unroll
            for (int j = 0; j < 4; j++)
                acc[i][j] = __builtin_amdgcn_mfma_f32_16x16x32_bf16(a[i], b[j], acc[i][j], 0, 0, 0);
    }
    __syncthreads();   // all h1-tile reads done -> safe to overwrite with h2
    ln_epilogue(b2, g2, be2, true);

    // ---------------- phase 3: h2 @ Wvut^T (K=256, barrier-free) ----------------
    zero_acc();
#pragma unroll 2
    for (int t = 0; t < 8; t++) {
        const int k0 = t * 32;
        short8 a[4], b[4];
#pragma unroll
        for (int j = 0; j < 4; j++)
            b[j] = *(const short8*)&Wvut[(size_t)(64 * wave + 16 * j + lr) * HIDN + k0 + lq * 8];
#pragma unroll
        for (int i = 0; i < 4; i++) a[i] = *(const short8*)&HT[16 * i + lr][k0 + lq * 8];
#pragma unroll
        for (int i = 0; i < 4; i++)
#pragma unroll
            for (int j = 0; j < 4; j++)
                acc[i][j] = __builtin_amdgcn_mfma_f32_16x16x32_bf16(a[i], b[j], acc[i][j], 0, 0, 0);
    }
    __syncthreads();   // h-tile dead -> us region writable

    // ---------------- score epilogue ----------------
    {
        float bjv[4];
#pragma unroll
        for (int j = 0; j < 4; j++) bjv[j] = bvu[wave * 64 + 16 * j + lr];
#pragma unroll
        for (int i = 0; i < 4; i++)
#pragma unroll
            for (int j = 0; j < 4; j++)
#pragma unroll
                for (int r = 0; r < 4; r++) acc[i][j][r] += bjv[j];

        float (*us)[129] = (float (*)[129])smem;            // sigmoid(u), padded stride
        float (*pw)[64]  = (float (*)[64])(smem + 33792);   // per-wave row partials
        if (wave >= 2) {
            const int cb = (wave - 2) * 64;
#pragma unroll
            for (int i = 0; i < 4; i++)
#pragma unroll
                for (int j = 0; j < 4; j++)
#pragma unroll
                    for (int r = 0; r < 4; r++)
                        us[16 * i + 4 * lq + r][cb + 16 * j + lr] =
                            1.0f / (1.0f + expf(-acc[i][j][r]));
        }
        __syncthreads();
        if (wave < 2) {
            const int cb = wave * 64;
            float wwj[4];
#pragma unroll
            for (int j = 0; j < 4; j++) wwj[j] = Ww[cb + 16 * j + lr];
#pragma unroll
            for (int i = 0; i < 4; i++)
#pragma unroll
                for (int r = 0; r < 4; r++) {
                    const int row = 16 * i + 4 * lq + r;
                    float s = 0.0f;
#pragma unroll
                    for (int j = 0; j < 4; j++)
                        s += tanhf(acc[i][j][r]) * us[row][cb + 16 * j + lr] * wwj[j];
#pragma unroll
                    for (int m = 1; m < 16; m <<= 1) s += __shfl_xor(s, m);
                    if (lr == 0) pw[wave][row] = s;
                }
        }
        __syncthreads();
        if (tid < 64) scores[row0 + tid] = pw[0][tid] + pw[1][tid] + bw[0];
    }
}

// Zp[b][col] = sum over 256 rows (b = seg*8+chunk) of exp(score[row])*h[row][col];
// Se[b] = sum of exp(score[row]). No max-subtraction: |score| <= sum|Ww| (~9), exp is fp32-safe,
// and softmax is shift-invariant so the result is mathematically identical.
__global__ __launch_bounds__(256) void pool_partial(const float* __restrict__ Scores,
                                                    const unsigned short* __restrict__ H,
                                                    float* __restrict__ Zp,
                                                    float* __restrict__ Se) {
    __shared__ float aw[256];
    __shared__ float part[8][256];
    __shared__ float sred[4];
    const int tid = threadIdx.x;
    const size_t rbase = (size_t)blockIdx.x * 256;
    const float e = expf(Scores[rbase + tid]);
    aw[tid] = e;
    float se = e;
#pragma unroll
    for (int o = 32; o > 0; o >>= 1) se += __shfl_down(se, o);
    if ((tid & 63) == 0) sred[tid >> 6] = se;
    __syncthreads();
    const int cg = tid & 31;
    const int rg = tid >> 5;
    float acc[8];
#pragma unroll
    for (int j = 0; j < 8; j++) acc[j] = 0.0f;
    for (int r = rg * 32; r < rg * 32 + 32; ++r) {
        short8 h8 = *(const short8*)&H[(rbase + r) * 256 + cg * 8];
        const float a = aw[r];
#pragma unroll
        for (int j = 0; j < 8; j++) acc[j] += a * bf2f((unsigned short)h8[j]);
    }
#pragma unroll
    for (int j = 0; j < 8; j++) part[rg][cg * 8 + j] = acc[j];
    __syncthreads();
    float s = 0.0f;
#pragma unroll
    for (int gq = 0; gq < 8; gq++) s += part[gq][tid];
    Zp[rbase + tid] = s;
    if (tid == 0) Se[blockIdx.x] = sred[0] + sred[1] + sred[2] + sred[3];
}

// z = (sum of 8 Zp partials)/(sum of 8 Se); logits = gelu(z @ Wc1 + bc1) @ Wc2 + bc2.
__global__ __launch_bounds__(256) void head_kernel(const float* __restrict__ Zp,
                                                   const float* __restrict__ Se,
                                                   const float* __restrict__ Wc1,
                                                   const float* __restrict__ bc1,
                                                   const float* __restrict__ Wc2,
                                                   const float* __restrict__ bc2,
                                                   float* __restrict__ Out) {
    __shared__ float zs[256];
    __shared__ float hs[128];
    __shared__ float red[4];
    const int seg = blockIdx.x, tid = threadIdx.x;
    float z = 0.0f;
#pragma unroll
    for (int c = 0; c < 8; c++) z += Zp[((size_t)seg * 8 + c) * 256 + tid];
    float den = 0.0f;
#pragma unroll
    for (int c = 0; c < 8; c++) den += Se[seg * 8 + c];
    zs[tid] = z / den;
    __syncthreads();
    if (tid < 128) {
        float acc = bc1[tid];
        for (int k = 0; k < 256; k++) acc += zs[k] * Wc1[k * 128 + tid];
        hs[tid] = gelu_exact(acc);
    }
    __syncthreads();
    const int cls = tid >> 7, j = tid & 127;
    float val = hs[j] * Wc2[j * 2 + cls];
#pragma unroll
    for (int o = 32; o > 0; o >>= 1) val += __shfl_down(val, o);
    if ((tid & 63) == 0) red[tid >> 6] = val;
    __syncthreads();
    if (tid < 2) Out[seg * 2 + tid] = red[tid * 2] + red[tid * 2 + 1] + bc2[tid];
}

extern "C" void kernel_launch(void* const* d_in, const int* in_sizes, int n_in,
                              void* d_out, int out_size, void* d_ws, size_t ws_size,
                              hipStream_t stream) {
    const float* x   = (const float*)d_in[0];
    const float* W1  = (const float*)d_in[2];
    const float* b1  = (const float*)d_in[3];
    const float* g1  = (const float*)d_in[4];
    const float* be1 = (const float*)d_in[5];
    const float* W2  = (const float*)d_in[6];
    const float* b2  = (const float*)d_in[7];
    const float* g2  = (const float*)d_in[8];
    const float* be2 = (const float*)d_in[9];
    const float* Wv  = (const float*)d_in[10];
    const float* bv  = (const float*)d_in[11];
    const float* Wu  = (const float*)d_in[12];
    const float* bu  = (const float*)d_in[13];
    const float* Ww  = (const float*)d_in[14];
    const float* bw  = (const float*)d_in[15];
    const float* Wc1 = (const float*)d_in[16];
    const float* bc1 = (const float*)d_in[17];
    const float* Wc2 = (const float*)d_in[18];
    const float* bc2 = (const float*)d_in[19];
    float* out = (float*)d_out;

    char* p = (char*)d_ws;
    unsigned short* h2b    = (unsigned short*)p; p += (size_t)N_TOK * HIDN * 2;  // 67 MB
    float*          scores = (float*)p;          p += (size_t)N_TOK * 4;
    unsigned short* W1t    = (unsigned short*)p; p += (size_t)HIDN * DIM * 2;
    unsigned short* W2t    = (unsigned short*)p; p += (size_t)HIDN * HIDN * 2;
    unsigned short* Wvut   = (unsigned short*)p; p += (size_t)HIDN * HIDN * 2;
    float*          bvu    = (float*)p;          p += 256 * 4;
    float*          Zp     = (float*)p;          p += (size_t)NSEG * 8 * HIDN * 4;
    float*          Se     = (float*)p;          p += (size_t)NSEG * 8 * 4;

    prep_weights<<<385, dim3(32, 8), 0, stream>>>(W1, W2, Wv, Wu, bv, bu, W1t, W2t, Wvut, bvu);

    fused_mlp_score<<<N_TOK / 64, 256, 0, stream>>>(
        x, W1t, W2t, Wvut,
        b1, g1, be1, b2, g2, be2,
        bvu, Ww, bw, h2b, scores);

    pool_partial<<<NSEG * 8, 256, 0, stream>>>(scores, h2b, Zp, Se);
    head_kernel<<<NSEG, 256, 0, stream>>>(Zp, Se, Wc1, bc1, Wc2, bc2, out);
}

// Round 5
// 914.211 us; speedup vs baseline: 1.4689x; 1.4689x over previous
//
#include <hip/hip_runtime.h>
#include <math.h>

#define N_TOK  131072
#define DIM    1024
#define HIDN   256
#define ATTN   128
#define NSEG   64
#define SEGLEN 2048
#define NCLS   2
#define EPSLN  1e-5f

typedef __attribute__((ext_vector_type(8))) short  short8;
typedef __attribute__((ext_vector_type(4))) float  f32x4;

__device__ __forceinline__ unsigned short f2bf(float f) {
    unsigned int u = __float_as_uint(f);
    u += 0x7fffu + ((u >> 16) & 1u);
    return (unsigned short)(u >> 16);
}
__device__ __forceinline__ float bf2f(unsigned short h) {
    return __uint_as_float(((unsigned int)h) << 16);
}
__device__ __forceinline__ float gelu_exact(float x) {
    return 0.5f * x * (1.0f + erff(x * 0.70710678118654752f));
}

// Weight prep: emit weights in MFMA-FRAGMENT order so the GEMM's B-loads are
// single coalesced dwordx4 per lane (1 KB contiguous per wave per fragment).
// Fragment layout: s8 index ((w*NT + t)*4 + j)*64 + lane holds, for lane (lr=lane&15,
// lq=lane>>4), elements W[k = t*32 + lq*8 + e][n = 64w + 16j + lr], e=0..7, as bf16.
//  blocks 0..127  : W1 (1024x256, NT=32) -> W1f  (32768 s8)
//  blocks 128..159: W2 (256x256,  NT=8)  -> W2f  (8192 s8)
//  blocks 160..191: [Wv|Wu] (256x(128+128), NT=8) -> Wvuf (8192 s8)
//  block  192     : bvu = [bv | bu]
__global__ __launch_bounds__(256) void prep_weights(const float* __restrict__ W1,
                                                    const float* __restrict__ W2,
                                                    const float* __restrict__ Wv,
                                                    const float* __restrict__ Wu,
                                                    const float* __restrict__ bv,
                                                    const float* __restrict__ bu,
                                                    unsigned short* __restrict__ W1f,
                                                    unsigned short* __restrict__ W2f,
                                                    unsigned short* __restrict__ Wvuf,
                                                    float* __restrict__ bvu) {
    const int b = blockIdx.x, tid = threadIdx.x;
    if (b == 192) {
        bvu[tid] = (tid < 128) ? bv[tid] : bu[tid - 128];
        return;
    }
    const int lane = tid & 63;
    const int lr = lane & 15, lq = lane >> 4;
    short8 sv;
    if (b < 128) {
        const int idx = b * 256 + tid;            // s8 index into W1f
        const int rem = idx >> 6;                 // (w*32+t)*4+j
        const int j = rem & 3, t = (rem >> 2) & 31, w = rem >> 7;
        const int n = 64 * w + 16 * j + lr;
        const int k = t * 32 + lq * 8;
#pragma unroll
        for (int e = 0; e < 8; e++) sv[e] = (short)f2bf(W1[(size_t)(k + e) * HIDN + n]);
        *(short8*)&W1f[(size_t)idx * 8] = sv;
    } else if (b < 160) {
        const int idx = (b - 128) * 256 + tid;
        const int rem = idx >> 6;
        const int j = rem & 3, t = (rem >> 2) & 7, w = rem >> 5;
        const int n = 64 * w + 16 * j + lr;
        const int k = t * 32 + lq * 8;
#pragma unroll
        for (int e = 0; e < 8; e++) sv[e] = (short)f2bf(W2[(size_t)(k + e) * HIDN + n]);
        *(short8*)&W2f[(size_t)idx * 8] = sv;
    } else {
        const int idx = (b - 160) * 256 + tid;
        const int rem = idx >> 6;
        const int j = rem & 3, t = (rem >> 2) & 7, w = rem >> 5;
        const int n = 64 * w + 16 * j + lr;
        const int k = t * 32 + lq * 8;
#pragma unroll
        for (int e = 0; e < 8; e++) {
            const float v = (n < 128) ? Wv[(size_t)(k + e) * ATTN + n]
                                      : Wu[(size_t)(k + e) * ATTN + (n - 128)];
            sv[e] = (short)f2bf(v);
        }
        *(short8*)&Wvuf[(size_t)idx * 8] = sv;
    }
}

// Mega-fused: h1=gelu(ln(x@W1+b1)); h2=gelu(ln(h1@W2+b2)) -> h2b; score via tanh/sigmoid/Ww.
// Phase 1 (K=1024): only x staged in LDS (double-buffered, ONE barrier/step);
//   W1 fragments loaded coalesced from W1f (L2-resident stream).
// Phases 2/3 (K=256): A from resident HT tile in LDS, B coalesced from W2f/Wvuf;
//   zero in-loop barriers.
// LDS map (35840 B):
//   [0..33792)  HT [64][264] ushort;  phase-1 As[2][64][40] (10240 B) and
//               score-epilogue us[64][129] f32 (33024 B) alias it (phase-disjoint).
//   [33792..35840) red [2][4][64] f32; score pw[2][64] aliases it.
__global__ __launch_bounds__(256, 4) void fused_mlp_score(
    const float* __restrict__ x,
    const unsigned short* __restrict__ W1f,
    const unsigned short* __restrict__ W2f,
    const unsigned short* __restrict__ Wvuf,
    const float* __restrict__ b1, const float* __restrict__ g1, const float* __restrict__ be1,
    const float* __restrict__ b2, const float* __restrict__ g2, const float* __restrict__ be2,
    const float* __restrict__ bvu, const float* __restrict__ Ww, const float* __restrict__ bw,
    unsigned short* __restrict__ h2b, float* __restrict__ scores) {
    __shared__ __align__(16) char smem[35840];
    auto As  = (unsigned short (*)[40])smem;        // [2*64][40] (buf*64+row)
    auto HT  = (unsigned short (*)[264])smem;       // [64][264]
    auto red = (float (*)[4][64])(smem + 33792);    // [2][4][64]

    const int tid  = threadIdx.x;
    const int wave = tid >> 6, lane = tid & 63;
    const int lr = lane & 15, lq = lane >> 4;
    const int srow = tid >> 2, skq = (tid & 3) * 8;
    const size_t row0 = (size_t)blockIdx.x * 64;

    f32x4 acc[4][4];
    auto zero_acc = [&]() {
#pragma unroll
        for (int i = 0; i < 4; i++)
#pragma unroll
            for (int j = 0; j < 4; j++) acc[i][j] = (f32x4)0.0f;
    };

    auto ln_epilogue = [&](const float* bias, const float* gamma, const float* beta, bool toGlobal) {
        float bjv[4];
#pragma unroll
        for (int j = 0; j < 4; j++) bjv[j] = bias[wave * 64 + 16 * j + lr];
#pragma unroll
        for (int i = 0; i < 4; i++)
#pragma unroll
            for (int j = 0; j < 4; j++)
#pragma unroll
                for (int r = 0; r < 4; r++) acc[i][j][r] += bjv[j];
#pragma unroll
        for (int i = 0; i < 4; i++)
#pragma unroll
            for (int r = 0; r < 4; r++) {
                float s = 0.0f, sq = 0.0f;
#pragma unroll
                for (int j = 0; j < 4; j++) { float v = acc[i][j][r]; s += v; sq += v * v; }
#pragma unroll
                for (int m = 1; m < 16; m <<= 1) { s += __shfl_xor(s, m); sq += __shfl_xor(sq, m); }
                if (lr == 0) {
                    red[0][wave][16 * i + 4 * lq + r] = s;
                    red[1][wave][16 * i + 4 * lq + r] = sq;
                }
            }
        __syncthreads();   // also orders: all prior HT/As reads done before HT writes below
        float gj[4], bej[4];
#pragma unroll
        for (int j = 0; j < 4; j++) {
            gj[j]  = gamma[wave * 64 + 16 * j + lr];
            bej[j] = beta[wave * 64 + 16 * j + lr];
        }
#pragma unroll
        for (int i = 0; i < 4; i++)
#pragma unroll
            for (int r = 0; r < 4; r++) {
                const int row = 16 * i + 4 * lq + r;
                const float s  = red[0][0][row] + red[0][1][row] + red[0][2][row] + red[0][3][row];
                const float sq = red[1][0][row] + red[1][1][row] + red[1][2][row] + red[1][3][row];
                const float mu  = s * (1.0f / HIDN);
                const float var = sq * (1.0f / HIDN) - mu * mu;
                const float rs  = rsqrtf(var + EPSLN);
#pragma unroll
                for (int j = 0; j < 4; j++) {
                    const int col = wave * 64 + 16 * j + lr;
                    const unsigned short hv = f2bf(gelu_exact((acc[i][j][r] - mu) * rs * gj[j] + bej[j]));
                    HT[row][col] = hv;
                    if (toGlobal) h2b[(row0 + row) * 256 + col] = hv;
                }
            }
        __syncthreads();   // HT fully written before the next phase reads it
    };

    auto loadX = [&](int t, short8& aw) {
        const float* p = &x[(row0 + srow) * DIM + t * 32 + skq];
        float4 v0 = *(const float4*)p;
        float4 v1 = *(const float4*)(p + 4);
        aw[0] = (short)f2bf(v0.x); aw[1] = (short)f2bf(v0.y);
        aw[2] = (short)f2bf(v0.z); aw[3] = (short)f2bf(v0.w);
        aw[4] = (short)f2bf(v1.x); aw[5] = (short)f2bf(v1.y);
        aw[6] = (short)f2bf(v1.z); aw[7] = (short)f2bf(v1.w);
    };

    // ---------------- phase 1: x @ W1 (K=1024), dbuf As, 1 barrier/step ----------------
    zero_acc();
    {
        short8 xw;
        loadX(0, xw);
        *(short8*)&As[0 * 64 + srow][skq] = xw;
        __syncthreads();
        const short8* wbase = (const short8*)W1f + (size_t)wave * 32 * 4 * 64 + lane;
        for (int t = 0; t < 32; ++t) {
            const bool more = (t + 1 < 32);
            if (more) loadX(t + 1, xw);
            const short8* wp = wbase + (size_t)t * 256;
            short8 b[4], a[4];
#pragma unroll
            for (int j = 0; j < 4; j++) b[j] = wp[j * 64];
#pragma unroll
            for (int i = 0; i < 4; i++) a[i] = *(const short8*)&As[(t & 1) * 64 + 16 * i + lr][lq * 8];
#pragma unroll
            for (int i = 0; i < 4; i++)
#pragma unroll
                for (int j = 0; j < 4; j++)
                    acc[i][j] = __builtin_amdgcn_mfma_f32_16x16x32_bf16(a[i], b[j], acc[i][j], 0, 0, 0);
            if (more) *(short8*)&As[((t + 1) & 1) * 64 + srow][skq] = xw;
            __syncthreads();
        }
    }
    ln_epilogue(b1, g1, be1, false);

    // ---------------- phase 2: h1 @ W2 (K=256), barrier-free ----------------
    zero_acc();
    {
        const short8* wbase = (const short8*)W2f + (size_t)wave * 8 * 4 * 64 + lane;
#pragma unroll 2
        for (int t = 0; t < 8; ++t) {
            const short8* wp = wbase + (size_t)t * 256;
            short8 b[4], a[4];
#pragma unroll
            for (int j = 0; j < 4; j++) b[j] = wp[j * 64];
#pragma unroll
            for (int i = 0; i < 4; i++) a[i] = *(const short8*)&HT[16 * i + lr][t * 32 + lq * 8];
#pragma unroll
            for (int i = 0; i < 4; i++)
#pragma unroll
                for (int j = 0; j < 4; j++)
                    acc[i][j] = __builtin_amdgcn_mfma_f32_16x16x32_bf16(a[i], b[j], acc[i][j], 0, 0, 0);
        }
    }
    ln_epilogue(b2, g2, be2, true);   // internal sync orders phase-2 reads before HT overwrite

    // ---------------- phase 3: h2 @ [Wv|Wu] (K=256), barrier-free ----------------
    zero_acc();
    {
        const short8* wbase = (const short8*)Wvuf + (size_t)wave * 8 * 4 * 64 + lane;
#pragma unroll 2
        for (int t = 0; t < 8; ++t) {
            const short8* wp = wbase + (size_t)t * 256;
            short8 b[4], a[4];
#pragma unroll
            for (int j = 0; j < 4; j++) b[j] = wp[j * 64];
#pragma unroll
            for (int i = 0; i < 4; i++) a[i] = *(const short8*)&HT[16 * i + lr][t * 32 + lq * 8];
#pragma unroll
            for (int i = 0; i < 4; i++)
#pragma unroll
                for (int j = 0; j < 4; j++)
                    acc[i][j] = __builtin_amdgcn_mfma_f32_16x16x32_bf16(a[i], b[j], acc[i][j], 0, 0, 0);
        }
    }
    __syncthreads();   // phase-3 HT reads drained -> us region writable

    // ---------------- score epilogue ----------------
    {
        float bjv[4];
#pragma unroll
        for (int j = 0; j < 4; j++) bjv[j] = bvu[wave * 64 + 16 * j + lr];
#pragma unroll
        for (int i = 0; i < 4; i++)
#pragma unroll
            for (int j = 0; j < 4; j++)
#pragma unroll
                for (int r = 0; r < 4; r++) acc[i][j][r] += bjv[j];

        float (*us)[129] = (float (*)[129])smem;            // sigmoid(u), padded stride
        float (*pw)[64]  = (float (*)[64])(smem + 33792);   // per-wave row partials
        if (wave >= 2) {
            const int cb = (wave - 2) * 64;
#pragma unroll
            for (int i = 0; i < 4; i++)
#pragma unroll
                for (int j = 0; j < 4; j++)
#pragma unroll
                    for (int r = 0; r < 4; r++)
                        us[16 * i + 4 * lq + r][cb + 16 * j + lr] =
                            1.0f / (1.0f + expf(-acc[i][j][r]));
        }
        __syncthreads();
        if (wave < 2) {
            const int cb = wave * 64;
            float wwj[4];
#pragma unroll
            for (int j = 0; j < 4; j++) wwj[j] = Ww[cb + 16 * j + lr];
#pragma unroll
            for (int i = 0; i < 4; i++)
#pragma unroll
                for (int r = 0; r < 4; r++) {
                    const int row = 16 * i + 4 * lq + r;
                    float s = 0.0f;
#pragma unroll
                    for (int j = 0; j < 4; j++)
                        s += tanhf(acc[i][j][r]) * us[row][cb + 16 * j + lr] * wwj[j];
#pragma unroll
                    for (int m = 1; m < 16; m <<= 1) s += __shfl_xor(s, m);
                    if (lr == 0) pw[wave][row] = s;
                }
        }
        __syncthreads();
        if (tid < 64) scores[row0 + tid] = pw[0][tid] + pw[1][tid] + bw[0];
    }
}

// Zp[b][col] = sum over 256 rows (b = seg*8+chunk) of exp(score[row])*h[row][col];
// Se[b] = sum of exp(score[row]). No max-subtraction: |score| <= sum|Ww| (~9), fp32-safe,
// softmax is shift-invariant so the result is identical.
__global__ __launch_bounds__(256) void pool_partial(const float* __restrict__ Scores,
                                                    const unsigned short* __restrict__ H,
                                                    float* __restrict__ Zp,
                                                    float* __restrict__ Se) {
    __shared__ float aw[256];
    __shared__ float part[8][256];
    __shared__ float sred[4];
    const int tid = threadIdx.x;
    const size_t rbase = (size_t)blockIdx.x * 256;
    const float e = expf(Scores[rbase + tid]);
    aw[tid] = e;
    float se = e;
#pragma unroll
    for (int o = 32; o > 0; o >>= 1) se += __shfl_down(se, o);
    if ((tid & 63) == 0) sred[tid >> 6] = se;
    __syncthreads();
    const int cg = tid & 31;
    const int rg = tid >> 5;
    float acc[8];
#pragma unroll
    for (int j = 0; j < 8; j++) acc[j] = 0.0f;
    for (int r = rg * 32; r < rg * 32 + 32; ++r) {
        short8 h8 = *(const short8*)&H[(rbase + r) * 256 + cg * 8];
        const float a = aw[r];
#pragma unroll
        for (int j = 0; j < 8; j++) acc[j] += a * bf2f((unsigned short)h8[j]);
    }
#pragma unroll
    for (int j = 0; j < 8; j++) part[rg][cg * 8 + j] = acc[j];
    __syncthreads();
    float s = 0.0f;
#pragma unroll
    for (int gq = 0; gq < 8; gq++) s += part[gq][tid];
    Zp[rbase + tid] = s;
    if (tid == 0) Se[blockIdx.x] = sred[0] + sred[1] + sred[2] + sred[3];
}

// z = (sum of 8 Zp partials)/(sum of 8 Se); logits = gelu(z @ Wc1 + bc1) @ Wc2 + bc2.
__global__ __launch_bounds__(256) void head_kernel(const float* __restrict__ Zp,
                                                   const float* __restrict__ Se,
                                                   const float* __restrict__ Wc1,
                                                   const float* __restrict__ bc1,
                                                   const float* __restrict__ Wc2,
                                                   const float* __restrict__ bc2,
                                                   float* __restrict__ Out) {
    __shared__ float zs[256];
    __shared__ float hs[128];
    __shared__ float red[4];
    const int seg = blockIdx.x, tid = threadIdx.x;
    float z = 0.0f;
#pragma unroll
    for (int c = 0; c < 8; c++) z += Zp[((size_t)seg * 8 + c) * 256 + tid];
    float den = 0.0f;
#pragma unroll
    for (int c = 0; c < 8; c++) den += Se[seg * 8 + c];
    zs[tid] = z / den;
    __syncthreads();
    if (tid < 128) {
        float acc = bc1[tid];
        for (int k = 0; k < 256; k++) acc += zs[k] * Wc1[k * 128 + tid];
        hs[tid] = gelu_exact(acc);
    }
    __syncthreads();
    const int cls = tid >> 7, j = tid & 127;
    float val = hs[j] * Wc2[j * 2 + cls];
#pragma unroll
    for (int o = 32; o > 0; o >>= 1) val += __shfl_down(val, o);
    if ((tid & 63) == 0) red[tid >> 6] = val;
    __syncthreads();
    if (tid < 2) Out[seg * 2 + tid] = red[tid * 2] + red[tid * 2 + 1] + bc2[tid];
}

extern "C" void kernel_launch(void* const* d_in, const int* in_sizes, int n_in,
                              void* d_out, int out_size, void* d_ws, size_t ws_size,
                              hipStream_t stream) {
    const float* x   = (const float*)d_in[0];
    const float* W1  = (const float*)d_in[2];
    const float* b1  = (const float*)d_in[3];
    const float* g1  = (const float*)d_in[4];
    const float* be1 = (const float*)d_in[5];
    const float* W2  = (const float*)d_in[6];
    const float* b2  = (const float*)d_in[7];
    const float* g2  = (const float*)d_in[8];
    const float* be2 = (const float*)d_in[9];
    const float* Wv  = (const float*)d_in[10];
    const float* bv  = (const float*)d_in[11];
    const float* Wu  = (const float*)d_in[12];
    const float* bu  = (const float*)d_in[13];
    const float* Ww  = (const float*)d_in[14];
    const float* bw  = (const float*)d_in[15];
    const float* Wc1 = (const float*)d_in[16];
    const float* bc1 = (const float*)d_in[17];
    const float* Wc2 = (const float*)d_in[18];
    const float* bc2 = (const float*)d_in[19];
    float* out = (float*)d_out;

    char* p = (char*)d_ws;
    unsigned short* h2b    = (unsigned short*)p; p += (size_t)N_TOK * HIDN * 2;  // 67 MB
    float*          scores = (float*)p;          p += (size_t)N_TOK * 4;
    unsigned short* W1f    = (unsigned short*)p; p += (size_t)HIDN * DIM * 2;
    unsigned short* W2f    = (unsigned short*)p; p += (size_t)HIDN * HIDN * 2;
    unsigned short* Wvuf   = (unsigned short*)p; p += (size_t)HIDN * HIDN * 2;
    float*          bvu    = (float*)p;          p += 256 * 4;
    float*          Zp     = (float*)p;          p += (size_t)NSEG * 8 * HIDN * 4;
    float*          Se     = (float*)p;          p += (size_t)NSEG * 8 * 4;

    prep_weights<<<193, 256, 0, stream>>>(W1, W2, Wv, Wu, bv, bu, W1f, W2f, Wvuf, bvu);

    fused_mlp_score<<<N_TOK / 64, 256, 0, stream>>>(
        x, W1f, W2f, Wvuf,
        b1, g1, be1, b2, g2, be2,
        bvu, Ww, bw, h2b, scores);

    pool_partial<<<NSEG * 8, 256, 0, stream>>>(scores, h2b, Zp, Se);
    head_kernel<<<NSEG, 256, 0, stream>>>(Zp, Se, Wc1, bc1, Wc2, bc2, out);
}

// Round 6
// 890.064 us; speedup vs baseline: 1.5088x; 1.0271x over previous
//
#include <hip/hip_runtime.h>
#include <math.h>

#define N_TOK  131072
#define DIM    1024
#define HIDN   256
#define ATTN   128
#define NSEG   64
#define NBLK   (N_TOK / 64)   // 2048 row-blocks, 32 per segment
#define NCLS   2
#define EPSLN  1e-5f

typedef __attribute__((ext_vector_type(8))) short  short8;
typedef __attribute__((ext_vector_type(4))) float  f32x4;

__device__ __forceinline__ unsigned short f2bf(float f) {
    unsigned int u = __float_as_uint(f);
    u += 0x7fffu + ((u >> 16) & 1u);
    return (unsigned short)(u >> 16);
}
__device__ __forceinline__ float bf2f(unsigned short h) {
    return __uint_as_float(((unsigned int)h) << 16);
}
__device__ __forceinline__ float gelu_exact(float x) {
    return 0.5f * x * (1.0f + erff(x * 0.70710678118654752f));
}
__device__ __forceinline__ short8 cvt8(float4 v0, float4 v1) {
    short8 r;
    r[0] = (short)f2bf(v0.x); r[1] = (short)f2bf(v0.y);
    r[2] = (short)f2bf(v0.z); r[3] = (short)f2bf(v0.w);
    r[4] = (short)f2bf(v1.x); r[5] = (short)f2bf(v1.y);
    r[6] = (short)f2bf(v1.z); r[7] = (short)f2bf(v1.w);
    return r;
}

// Weight prep -> MFMA-fragment order (one coalesced dwordx4 per lane per fragment).
// W1f/W2f fragment ((w*NT+t)*4+j)*64+lane: lane(lr,lq) holds W[k=t*32+lq*8+e][n=64w+16j+lr].
// Wvuf PAIRED fragment order: j in {0,1} -> Wv col 32w+16j+lr ; j in {2,3} -> Wu col
// 32w+16(j-2)+lr  => lane lr holds v-col c (frag j) and u-col c (frag j+2) for the SAME c.
//  blocks 0..127  : W1 (NT=32) -> W1f ;  128..159: W2 (NT=8) -> W2f ;  160..191: Wv/Wu -> Wvuf
__global__ __launch_bounds__(256) void prep_weights(const float* __restrict__ W1,
                                                    const float* __restrict__ W2,
                                                    const float* __restrict__ Wv,
                                                    const float* __restrict__ Wu,
                                                    unsigned short* __restrict__ W1f,
                                                    unsigned short* __restrict__ W2f,
                                                    unsigned short* __restrict__ Wvuf) {
    const int b = blockIdx.x, tid = threadIdx.x;
    const int lane = tid & 63;
    const int lr = lane & 15, lq = lane >> 4;
    short8 sv;
    if (b < 128) {
        const int idx = b * 256 + tid;
        const int rem = idx >> 6;                 // (w*32+t)*4+j
        const int j = rem & 3, t = (rem >> 2) & 31, w = rem >> 7;
        const int n = 64 * w + 16 * j + lr;
        const int k = t * 32 + lq * 8;
#pragma unroll
        for (int e = 0; e < 8; e++) sv[e] = (short)f2bf(W1[(size_t)(k + e) * HIDN + n]);
        *(short8*)&W1f[(size_t)idx * 8] = sv;
    } else if (b < 160) {
        const int idx = (b - 128) * 256 + tid;
        const int rem = idx >> 6;                 // (w*8+t)*4+j
        const int j = rem & 3, t = (rem >> 2) & 7, w = rem >> 5;
        const int n = 64 * w + 16 * j + lr;
        const int k = t * 32 + lq * 8;
#pragma unroll
        for (int e = 0; e < 8; e++) sv[e] = (short)f2bf(W2[(size_t)(k + e) * HIDN + n]);
        *(short8*)&W2f[(size_t)idx * 8] = sv;
    } else {
        const int idx = (b - 160) * 256 + tid;
        const int rem = idx >> 6;                 // (w*8+t)*4+j
        const int j = rem & 3, t = (rem >> 2) & 7, w = rem >> 5;
        const int col = 32 * w + 16 * (j & 1) + lr;
        const int k = t * 32 + lq * 8;
        const float* src = (j < 2) ? Wv : Wu;
#pragma unroll
        for (int e = 0; e < 8; e++) sv[e] = (short)f2bf(src[(size_t)(k + e) * ATTN + col]);
        *(short8*)&Wvuf[(size_t)idx * 8] = sv;
    }
}

// Mega-fused per 64-row block:
//  h1=gelu(ln(x@W1+b1)); h2=gelu(ln(h1@W2+b2)) kept in LDS;
//  score[row]=sum_c tanh(v_c)*sigmoid(u_c)*Ww_c + bw (lane-local via paired Wvuf);
//  Zp[blk][col]=sum_row exp(score)*h2[row][col]; Se[blk]=sum_row exp(score).
// Deep register prefetch: x 3 K-steps ahead, W fragments 1 step ahead (all phases).
// LDS map (35840 B): [0..33792) HT[64][264] u16 (phase-1 As[2][64][40]=10240 B aliases it);
//                    [33792..35840) red[2][4][64] f32 (score pw[4][64]+es[64] alias it).
__global__ __launch_bounds__(256, 3) void fused_mlp_score(
    const float* __restrict__ x,
    const unsigned short* __restrict__ W1f,
    const unsigned short* __restrict__ W2f,
    const unsigned short* __restrict__ Wvuf,
    const float* __restrict__ b1, const float* __restrict__ g1, const float* __restrict__ be1,
    const float* __restrict__ b2, const float* __restrict__ g2, const float* __restrict__ be2,
    const float* __restrict__ bv, const float* __restrict__ bu,
    const float* __restrict__ Ww, const float* __restrict__ bw,
    float* __restrict__ Zp, float* __restrict__ Se) {
    __shared__ __align__(16) char smem[35840];
    auto As  = (unsigned short (*)[40])smem;        // [2*64][40]
    auto HT  = (unsigned short (*)[264])smem;       // [64][264]
    auto red = (float (*)[4][64])(smem + 33792);    // [2][4][64]

    const int tid  = threadIdx.x;
    const int wave = tid >> 6, lane = tid & 63;
    const int lr = lane & 15, lq = lane >> 4;
    const int srow = tid >> 2, skq = (tid & 3) * 8;
    const size_t row0 = (size_t)blockIdx.x * 64;

    f32x4 acc[4][4];
    auto zero_acc = [&]() {
#pragma unroll
        for (int i = 0; i < 4; i++)
#pragma unroll
            for (int j = 0; j < 4; j++) acc[i][j] = (f32x4)0.0f;
    };

    auto ln_epilogue = [&](const float* bias, const float* gamma, const float* beta) {
        float bjv[4];
#pragma unroll
        for (int j = 0; j < 4; j++) bjv[j] = bias[wave * 64 + 16 * j + lr];
#pragma unroll
        for (int i = 0; i < 4; i++)
#pragma unroll
            for (int j = 0; j < 4; j++)
#pragma unroll
                for (int r = 0; r < 4; r++) acc[i][j][r] += bjv[j];
#pragma unroll
        for (int i = 0; i < 4; i++)
#pragma unroll
            for (int r = 0; r < 4; r++) {
                float s = 0.0f, sq = 0.0f;
#pragma unroll
                for (int j = 0; j < 4; j++) { float v = acc[i][j][r]; s += v; sq += v * v; }
#pragma unroll
                for (int m = 1; m < 16; m <<= 1) { s += __shfl_xor(s, m); sq += __shfl_xor(sq, m); }
                if (lr == 0) {
                    red[0][wave][16 * i + 4 * lq + r] = s;
                    red[1][wave][16 * i + 4 * lq + r] = sq;
                }
            }
        __syncthreads();
        float gj[4], bej[4];
#pragma unroll
        for (int j = 0; j < 4; j++) {
            gj[j]  = gamma[wave * 64 + 16 * j + lr];
            bej[j] = beta[wave * 64 + 16 * j + lr];
        }
#pragma unroll
        for (int i = 0; i < 4; i++)
#pragma unroll
            for (int r = 0; r < 4; r++) {
                const int row = 16 * i + 4 * lq + r;
                const float s  = red[0][0][row] + red[0][1][row] + red[0][2][row] + red[0][3][row];
                const float sq = red[1][0][row] + red[1][1][row] + red[1][2][row] + red[1][3][row];
                const float mu  = s * (1.0f / HIDN);
                const float var = sq * (1.0f / HIDN) - mu * mu;
                const float rs  = rsqrtf(var + EPSLN);
#pragma unroll
                for (int j = 0; j < 4; j++)
                    HT[row][wave * 64 + 16 * j + lr] =
                        f2bf(gelu_exact((acc[i][j][r] - mu) * rs * gj[j] + bej[j]));
            }
        __syncthreads();   // HT complete before the next phase reads it
    };

    // ---------- phase 1: x @ W1 (K=1024), x prefetch depth 3, W depth 1 ----------
    zero_acc();
    {
        const float* xrow = &x[(row0 + srow) * DIM + skq];
        const short8* wb = (const short8*)W1f + (size_t)wave * (32 * 4 * 64) + lane;
        float4 x0[3], x1[3];
        short8 bq[2][4];
#pragma unroll
        for (int s = 0; s < 3; ++s) {
            x0[s] = *(const float4*)(xrow + 32 * s);
            x1[s] = *(const float4*)(xrow + 32 * s + 4);
        }
#pragma unroll
        for (int j = 0; j < 4; ++j) bq[0][j] = wb[j * 64];
        *(short8*)&As[srow][skq] = cvt8(x0[0], x1[0]);
        __syncthreads();
#pragma unroll
        for (int t = 0; t < 32; ++t) {
            if (t + 3 < 32) {
                x0[(t + 3) % 3] = *(const float4*)(xrow + 32 * (t + 3));
                x1[(t + 3) % 3] = *(const float4*)(xrow + 32 * (t + 3) + 4);
            }
            if (t + 1 < 32) {
                const short8* wp = wb + (size_t)(t + 1) * 256;
#pragma unroll
                for (int j = 0; j < 4; ++j) bq[(t + 1) & 1][j] = wp[j * 64];
            }
            short8 a[4];
#pragma unroll
            for (int i = 0; i < 4; ++i)
                a[i] = *(const short8*)&As[(t & 1) * 64 + 16 * i + lr][lq * 8];
#pragma unroll
            for (int i = 0; i < 4; ++i)
#pragma unroll
                for (int j = 0; j < 4; ++j)
                    acc[i][j] = __builtin_amdgcn_mfma_f32_16x16x32_bf16(a[i], bq[t & 1][j], acc[i][j], 0, 0, 0);
            if (t + 1 < 32)
                *(short8*)&As[((t + 1) & 1) * 64 + srow][skq] = cvt8(x0[(t + 1) % 3], x1[(t + 1) % 3]);
            __syncthreads();
        }
    }
    ln_epilogue(b1, g1, be1);

    // ---------- phases 2/3: HT @ W (K=256), barrier-free, W prefetch depth 1 ----------
    auto gemm_ht = [&](const short8* wb) {
        short8 bq[2][4];
#pragma unroll
        for (int j = 0; j < 4; ++j) bq[0][j] = wb[j * 64];
#pragma unroll
        for (int t = 0; t < 8; ++t) {
            if (t + 1 < 8) {
                const short8* wp = wb + (size_t)(t + 1) * 256;
#pragma unroll
                for (int j = 0; j < 4; ++j) bq[(t + 1) & 1][j] = wp[j * 64];
            }
            short8 a[4];
#pragma unroll
            for (int i = 0; i < 4; ++i)
                a[i] = *(const short8*)&HT[16 * i + lr][t * 32 + lq * 8];
#pragma unroll
            for (int i = 0; i < 4; ++i)
#pragma unroll
                for (int j = 0; j < 4; ++j)
                    acc[i][j] = __builtin_amdgcn_mfma_f32_16x16x32_bf16(a[i], bq[t & 1][j], acc[i][j], 0, 0, 0);
        }
    };

    zero_acc();
    gemm_ht((const short8*)W2f + (size_t)wave * (8 * 4 * 64) + lane);
    ln_epilogue(b2, g2, be2);   // h2 now resident in HT

    zero_acc();
    gemm_ht((const short8*)Wvuf + (size_t)wave * (8 * 4 * 64) + lane);

    // ---------- score (lane-local v/u pairing) + softmax-pool epilogue ----------
    {
        float bvv[2], buu[2], wwj[2];
#pragma unroll
        for (int j = 0; j < 2; ++j) {
            bvv[j] = bv[32 * wave + 16 * j + lr];
            buu[j] = bu[32 * wave + 16 * j + lr];
            wwj[j] = Ww[32 * wave + 16 * j + lr];
        }
        float (*pw)[64] = (float (*)[64])(smem + 33792);   // [4][64]
        float* es = (float*)(smem + 33792 + 1024);         // [64]
#pragma unroll
        for (int i = 0; i < 4; ++i)
#pragma unroll
            for (int r = 0; r < 4; ++r) {
                const int row = 16 * i + 4 * lq + r;
                float s = 0.0f;
#pragma unroll
                for (int j = 0; j < 2; ++j) {
                    const float vv = acc[i][j][r] + bvv[j];
                    const float uu = acc[i][j + 2][r] + buu[j];
                    s += tanhf(vv) * (1.0f / (1.0f + expf(-uu))) * wwj[j];
                }
#pragma unroll
                for (int m = 1; m < 16; m <<= 1) s += __shfl_xor(s, m);
                if (lr == 0) pw[wave][row] = s;
            }
        __syncthreads();
        if (tid < 64) {
            const float sc = pw[0][tid] + pw[1][tid] + pw[2][tid] + pw[3][tid] + bw[0];
            const float e = expf(sc);   // no max-subtraction: |sc| <= sum|Ww| (~9), fp32-safe
            es[tid] = e;
            float t2 = e;
#pragma unroll
            for (int o = 32; o > 0; o >>= 1) t2 += __shfl_down(t2, o);
            if (tid == 0) Se[blockIdx.x] = t2;
        }
        __syncthreads();
        float pacc = 0.0f;
#pragma unroll 8
        for (int row = 0; row < 64; ++row) pacc += es[row] * bf2f(HT[row][tid]);
        Zp[(size_t)blockIdx.x * 256 + tid] = pacc;
    }
}

// z = (sum of 32 Zp partials) / (sum of 32 Se); logits = gelu(z@Wc1+bc1)@Wc2 + bc2.
__global__ __launch_bounds__(256) void head_kernel(const float* __restrict__ Zp,
                                                   const float* __restrict__ Se,
                                                   const float* __restrict__ Wc1,
                                                   const float* __restrict__ bc1,
                                                   const float* __restrict__ Wc2,
                                                   const float* __restrict__ bc2,
                                                   float* __restrict__ Out) {
    __shared__ float zs[256];
    __shared__ float hs[128];
    __shared__ float red[4];
    const int seg = blockIdx.x, tid = threadIdx.x;
    float z = 0.0f;
#pragma unroll
    for (int c = 0; c < 32; ++c) z += Zp[((size_t)seg * 32 + c) * 256 + tid];
    float den = 0.0f;
#pragma unroll
    for (int c = 0; c < 32; ++c) den += Se[seg * 32 + c];
    zs[tid] = z / den;
    __syncthreads();
    if (tid < 128) {
        float acc = bc1[tid];
        for (int k = 0; k < 256; k++) acc += zs[k] * Wc1[k * 128 + tid];
        hs[tid] = gelu_exact(acc);
    }
    __syncthreads();
    const int cls = tid >> 7, j = tid & 127;
    float val = hs[j] * Wc2[j * 2 + cls];
#pragma unroll
    for (int o = 32; o > 0; o >>= 1) val += __shfl_down(val, o);
    if ((tid & 63) == 0) red[tid >> 6] = val;
    __syncthreads();
    if (tid < 2) Out[seg * 2 + tid] = red[tid * 2] + red[tid * 2 + 1] + bc2[tid];
}

extern "C" void kernel_launch(void* const* d_in, const int* in_sizes, int n_in,
                              void* d_out, int out_size, void* d_ws, size_t ws_size,
                              hipStream_t stream) {
    const float* x   = (const float*)d_in[0];
    const float* W1  = (const float*)d_in[2];
    const float* b1  = (const float*)d_in[3];
    const float* g1  = (const float*)d_in[4];
    const float* be1 = (const float*)d_in[5];
    const float* W2  = (const float*)d_in[6];
    const float* b2  = (const float*)d_in[7];
    const float* g2  = (const float*)d_in[8];
    const float* be2 = (const float*)d_in[9];
    const float* Wv  = (const float*)d_in[10];
    const float* bv  = (const float*)d_in[11];
    const float* Wu  = (const float*)d_in[12];
    const float* bu  = (const float*)d_in[13];
    const float* Ww  = (const float*)d_in[14];
    const float* bw  = (const float*)d_in[15];
    const float* Wc1 = (const float*)d_in[16];
    const float* bc1 = (const float*)d_in[17];
    const float* Wc2 = (const float*)d_in[18];
    const float* bc2 = (const float*)d_in[19];
    float* out = (float*)d_out;

    char* p = (char*)d_ws;
    unsigned short* W1f  = (unsigned short*)p; p += (size_t)HIDN * DIM * 2;
    unsigned short* W2f  = (unsigned short*)p; p += (size_t)HIDN * HIDN * 2;
    unsigned short* Wvuf = (unsigned short*)p; p += (size_t)HIDN * HIDN * 2;
    float*          Zp   = (float*)p;          p += (size_t)NBLK * HIDN * 4;
    float*          Se   = (float*)p;          p += (size_t)NBLK * 4;

    prep_weights<<<192, 256, 0, stream>>>(W1, W2, Wv, Wu, W1f, W2f, Wvuf);

    fused_mlp_score<<<NBLK, 256, 0, stream>>>(
        x, W1f, W2f, Wvuf,
        b1, g1, be1, b2, g2, be2,
        bv, bu, Ww, bw, Zp, Se);

    head_kernel<<<NSEG, 256, 0, stream>>>(Zp, Se, Wc1, bc1, Wc2, bc2, out);
}

// Round 7
// 854.605 us; speedup vs baseline: 1.5714x; 1.0415x over previous
//
#include <hip/hip_runtime.h>
#include <math.h>

#define N_TOK  131072
#define DIM    1024
#define HIDN   256
#define ATTN   128
#define NSEG   64
#define NBLK   (N_TOK / 64)   // 2048 row-blocks, 32 per segment
#define NCLS   2
#define EPSLN  1e-5f

typedef __attribute__((ext_vector_type(8))) short  short8;
typedef __attribute__((ext_vector_type(4))) float  f32x4;

__device__ __forceinline__ unsigned short f2bf(float f) {
    unsigned int u = __float_as_uint(f);
    u += 0x7fffu + ((u >> 16) & 1u);
    return (unsigned short)(u >> 16);
}
__device__ __forceinline__ float bf2f(unsigned short h) {
    return __uint_as_float(((unsigned int)h) << 16);
}
__device__ __forceinline__ float gelu_exact(float x) {
    return 0.5f * x * (1.0f + erff(x * 0.70710678118654752f));
}
// Branchless GELU: erf via Abramowitz-Stegun 7.1.26 (|eps| <= 1.5e-7).
// ~15 VALU ops (v_rcp + 5-term Horner + v_exp) vs ~30 for libm erff.
__device__ __forceinline__ float gelu_fast(float x) {
    const float z  = x * 0.70710678118654752f;
    const float az = fabsf(z);
    const float t  = __builtin_amdgcn_rcpf(fmaf(0.3275911f, az, 1.0f));
    float p = fmaf(t, 1.061405429f, -1.453152027f);
    p = fmaf(t, p, 1.421413741f);
    p = fmaf(t, p, -0.284496736f);
    p = fmaf(t, p, 0.254829592f);
    p *= t;
    const float e  = __expf(-z * z);
    float er = fmaf(-p, e, 1.0f);
    er = copysignf(er, z);
    return 0.5f * x * (1.0f + er);
}
__device__ __forceinline__ float tanh_fast(float x) {
    const float e = __expf(-2.0f * fabsf(x));
    const float r = (1.0f - e) * __builtin_amdgcn_rcpf(1.0f + e);
    return copysignf(r, x);
}
__device__ __forceinline__ float sigmoid_fast(float x) {
    return __builtin_amdgcn_rcpf(1.0f + __expf(-x));
}
__device__ __forceinline__ short8 cvt8(float4 v0, float4 v1) {
    short8 r;
    r[0] = (short)f2bf(v0.x); r[1] = (short)f2bf(v0.y);
    r[2] = (short)f2bf(v0.z); r[3] = (short)f2bf(v0.w);
    r[4] = (short)f2bf(v1.x); r[5] = (short)f2bf(v1.y);
    r[6] = (short)f2bf(v1.z); r[7] = (short)f2bf(v1.w);
    return r;
}

// Weight prep -> MFMA-fragment order (one coalesced dwordx4 per lane per fragment).
// W1f/W2f fragment ((w*NT+t)*4+j)*64+lane: lane(lr,lq) holds W[k=t*32+lq*8+e][n=64w+16j+lr].
// Wvuf PAIRED fragment order: j in {0,1} -> Wv col 32w+16j+lr ; j in {2,3} -> Wu col
// 32w+16(j-2)+lr  => lane lr holds v-col c (frag j) and u-col c (frag j+2) for the SAME c.
//  blocks 0..127  : W1 (NT=32) -> W1f ;  128..159: W2 (NT=8) -> W2f ;  160..191: Wv/Wu -> Wvuf
__global__ __launch_bounds__(256) void prep_weights(const float* __restrict__ W1,
                                                    const float* __restrict__ W2,
                                                    const float* __restrict__ Wv,
                                                    const float* __restrict__ Wu,
                                                    unsigned short* __restrict__ W1f,
                                                    unsigned short* __restrict__ W2f,
                                                    unsigned short* __restrict__ Wvuf) {
    const int b = blockIdx.x, tid = threadIdx.x;
    const int lane = tid & 63;
    const int lr = lane & 15, lq = lane >> 4;
    short8 sv;
    if (b < 128) {
        const int idx = b * 256 + tid;
        const int rem = idx >> 6;                 // (w*32+t)*4+j
        const int j = rem & 3, t = (rem >> 2) & 31, w = rem >> 7;
        const int n = 64 * w + 16 * j + lr;
        const int k = t * 32 + lq * 8;
#pragma unroll
        for (int e = 0; e < 8; e++) sv[e] = (short)f2bf(W1[(size_t)(k + e) * HIDN + n]);
        *(short8*)&W1f[(size_t)idx * 8] = sv;
    } else if (b < 160) {
        const int idx = (b - 128) * 256 + tid;
        const int rem = idx >> 6;                 // (w*8+t)*4+j
        const int j = rem & 3, t = (rem >> 2) & 7, w = rem >> 5;
        const int n = 64 * w + 16 * j + lr;
        const int k = t * 32 + lq * 8;
#pragma unroll
        for (int e = 0; e < 8; e++) sv[e] = (short)f2bf(W2[(size_t)(k + e) * HIDN + n]);
        *(short8*)&W2f[(size_t)idx * 8] = sv;
    } else {
        const int idx = (b - 160) * 256 + tid;
        const int rem = idx >> 6;                 // (w*8+t)*4+j
        const int j = rem & 3, t = (rem >> 2) & 7, w = rem >> 5;
        const int col = 32 * w + 16 * (j & 1) + lr;
        const int k = t * 32 + lq * 8;
        const float* src = (j < 2) ? Wv : Wu;
#pragma unroll
        for (int e = 0; e < 8; e++) sv[e] = (short)f2bf(src[(size_t)(k + e) * ATTN + col]);
        *(short8*)&Wvuf[(size_t)idx * 8] = sv;
    }
}

// Mega-fused per 64-row block:
//  h1=gelu(ln(x@W1+b1)); h2=gelu(ln(h1@W2+b2)) kept in LDS;
//  score[row]=sum_c tanh(v_c)*sigmoid(u_c)*Ww_c + bw (lane-local via paired Wvuf);
//  Zp[blk][col]=sum_row exp(score)*h2[row][col]; Se[blk]=sum_row exp(score).
// x register-prefetch depth 3; W fragments prefetch depth 1; phase-2/3 step-0 W fragments
// issued BEFORE the preceding LN epilogue (L2 latency hides under epilogue VALU).
// LDS map (35840 B): [0..33792) HT[64][264] u16 (phase-1 As[2][64][40]=10240 B aliases it);
//                    [33792..35840) red[2][4][64] f32 (score pw[4][64]+es[64] alias it).
__global__ __launch_bounds__(256, 3) void fused_mlp_score(
    const float* __restrict__ x,
    const unsigned short* __restrict__ W1f,
    const unsigned short* __restrict__ W2f,
    const unsigned short* __restrict__ Wvuf,
    const float* __restrict__ b1, const float* __restrict__ g1, const float* __restrict__ be1,
    const float* __restrict__ b2, const float* __restrict__ g2, const float* __restrict__ be2,
    const float* __restrict__ bv, const float* __restrict__ bu,
    const float* __restrict__ Ww, const float* __restrict__ bw,
    float* __restrict__ Zp, float* __restrict__ Se) {
    __shared__ __align__(16) char smem[35840];
    auto As  = (unsigned short (*)[40])smem;        // [2*64][40]
    auto HT  = (unsigned short (*)[264])smem;       // [64][264]
    auto red = (float (*)[4][64])(smem + 33792);    // [2][4][64]

    const int tid  = threadIdx.x;
    const int wave = tid >> 6, lane = tid & 63;
    const int lr = lane & 15, lq = lane >> 4;
    const int srow = tid >> 2, skq = (tid & 3) * 8;
    const size_t row0 = (size_t)blockIdx.x * 64;

    f32x4 acc[4][4];
    auto zero_acc = [&]() {
#pragma unroll
        for (int i = 0; i < 4; i++)
#pragma unroll
            for (int j = 0; j < 4; j++) acc[i][j] = (f32x4)0.0f;
    };

    auto ln_epilogue = [&](const float* bias, const float* gamma, const float* beta) {
        float bjv[4];
#pragma unroll
        for (int j = 0; j < 4; j++) bjv[j] = bias[wave * 64 + 16 * j + lr];
#pragma unroll
        for (int i = 0; i < 4; i++)
#pragma unroll
            for (int j = 0; j < 4; j++)
#pragma unroll
                for (int r = 0; r < 4; r++) acc[i][j][r] += bjv[j];
#pragma unroll
        for (int i = 0; i < 4; i++)
#pragma unroll
            for (int r = 0; r < 4; r++) {
                float s = 0.0f, sq = 0.0f;
#pragma unroll
                for (int j = 0; j < 4; j++) { float v = acc[i][j][r]; s += v; sq += v * v; }
#pragma unroll
                for (int m = 1; m < 16; m <<= 1) { s += __shfl_xor(s, m); sq += __shfl_xor(sq, m); }
                if (lr == 0) {
                    red[0][wave][16 * i + 4 * lq + r] = s;
                    red[1][wave][16 * i + 4 * lq + r] = sq;
                }
            }
        __syncthreads();
        float gj[4], bej[4];
#pragma unroll
        for (int j = 0; j < 4; j++) {
            gj[j]  = gamma[wave * 64 + 16 * j + lr];
            bej[j] = beta[wave * 64 + 16 * j + lr];
        }
#pragma unroll
        for (int i = 0; i < 4; i++)
#pragma unroll
            for (int r = 0; r < 4; r++) {
                const int row = 16 * i + 4 * lq + r;
                const float s  = red[0][0][row] + red[0][1][row] + red[0][2][row] + red[0][3][row];
                const float sq = red[1][0][row] + red[1][1][row] + red[1][2][row] + red[1][3][row];
                const float mu  = s * (1.0f / HIDN);
                const float var = sq * (1.0f / HIDN) - mu * mu;
                const float rs  = rsqrtf(var + EPSLN);
#pragma unroll
                for (int j = 0; j < 4; j++)
                    HT[row][wave * 64 + 16 * j + lr] =
                        f2bf(gelu_fast((acc[i][j][r] - mu) * rs * gj[j] + bej[j]));
            }
        __syncthreads();   // HT complete before the next phase reads it
    };

    // ---------- phase 1: x @ W1 (K=1024), x prefetch depth 3, W depth 1 ----------
    zero_acc();
    {
        const float* xrow = &x[(row0 + srow) * DIM + skq];
        const short8* wb = (const short8*)W1f + (size_t)wave * (32 * 4 * 64) + lane;
        float4 x0[3], x1[3];
        short8 bq[2][4];
#pragma unroll
        for (int s = 0; s < 3; ++s) {
            x0[s] = *(const float4*)(xrow + 32 * s);
            x1[s] = *(const float4*)(xrow + 32 * s + 4);
        }
#pragma unroll
        for (int j = 0; j < 4; ++j) bq[0][j] = wb[j * 64];
        *(short8*)&As[srow][skq] = cvt8(x0[0], x1[0]);
        __syncthreads();
#pragma unroll
        for (int t = 0; t < 32; ++t) {
            if (t + 3 < 32) {
                x0[(t + 3) % 3] = *(const float4*)(xrow + 32 * (t + 3));
                x1[(t + 3) % 3] = *(const float4*)(xrow + 32 * (t + 3) + 4);
            }
            if (t + 1 < 32) {
                const short8* wp = wb + (size_t)(t + 1) * 256;
#pragma unroll
                for (int j = 0; j < 4; ++j) bq[(t + 1) & 1][j] = wp[j * 64];
            }
            short8 a[4];
#pragma unroll
            for (int i = 0; i < 4; ++i)
                a[i] = *(const short8*)&As[(t & 1) * 64 + 16 * i + lr][lq * 8];
#pragma unroll
            for (int i = 0; i < 4; ++i)
#pragma unroll
                for (int j = 0; j < 4; ++j)
                    acc[i][j] = __builtin_amdgcn_mfma_f32_16x16x32_bf16(a[i], bq[t & 1][j], acc[i][j], 0, 0, 0);
            if (t + 1 < 32)
                *(short8*)&As[((t + 1) & 1) * 64 + srow][skq] = cvt8(x0[(t + 1) % 3], x1[(t + 1) % 3]);
            __syncthreads();
        }
    }

    const short8* w2b = (const short8*)W2f  + (size_t)wave * (8 * 4 * 64) + lane;
    const short8* wvb = (const short8*)Wvuf + (size_t)wave * (8 * 4 * 64) + lane;

    // pre-issue phase-2 step-0 W fragments: L2 latency hides under epilogue VALU
    short8 pre[4];
#pragma unroll
    for (int j = 0; j < 4; ++j) pre[j] = w2b[j * 64];

    ln_epilogue(b1, g1, be1);

    // ---------- phases 2/3: HT @ W (K=256), barrier-free, W prefetch depth 1 ----------
    auto gemm_ht = [&](const short8* wb, const short8* pre0) {
        short8 bq[2][4];
#pragma unroll
        for (int j = 0; j < 4; ++j) bq[0][j] = pre0[j];
#pragma unroll
        for (int t = 0; t < 8; ++t) {
            if (t + 1 < 8) {
                const short8* wp = wb + (size_t)(t + 1) * 256;
#pragma unroll
                for (int j = 0; j < 4; ++j) bq[(t + 1) & 1][j] = wp[j * 64];
            }
            short8 a[4];
#pragma unroll
            for (int i = 0; i < 4; ++i)
                a[i] = *(const short8*)&HT[16 * i + lr][t * 32 + lq * 8];
#pragma unroll
            for (int i = 0; i < 4; ++i)
#pragma unroll
                for (int j = 0; j < 4; ++j)
                    acc[i][j] = __builtin_amdgcn_mfma_f32_16x16x32_bf16(a[i], bq[t & 1][j], acc[i][j], 0, 0, 0);
        }
    };

    zero_acc();
    gemm_ht(w2b, pre);

    // pre-issue phase-3 step-0 W fragments before the second epilogue
#pragma unroll
    for (int j = 0; j < 4; ++j) pre[j] = wvb[j * 64];

    ln_epilogue(b2, g2, be2);   // h2 now resident in HT

    zero_acc();
    gemm_ht(wvb, pre);

    // ---------- score (lane-local v/u pairing) + softmax-pool epilogue ----------
    {
        float bvv[2], buu[2], wwj[2];
#pragma unroll
        for (int j = 0; j < 2; ++j) {
            bvv[j] = bv[32 * wave + 16 * j + lr];
            buu[j] = bu[32 * wave + 16 * j + lr];
            wwj[j] = Ww[32 * wave + 16 * j + lr];
        }
        float (*pw)[64] = (float (*)[64])(smem + 33792);   // [4][64]
        float* es = (float*)(smem + 33792 + 1024);         // [64]
#pragma unroll
        for (int i = 0; i < 4; ++i)
#pragma unroll
            for (int r = 0; r < 4; ++r) {
                const int row = 16 * i + 4 * lq + r;
                float s = 0.0f;
#pragma unroll
                for (int j = 0; j < 2; ++j) {
                    const float vv = acc[i][j][r] + bvv[j];
                    const float uu = acc[i][j + 2][r] + buu[j];
                    s += tanh_fast(vv) * sigmoid_fast(uu) * wwj[j];
                }
#pragma unroll
                for (int m = 1; m < 16; m <<= 1) s += __shfl_xor(s, m);
                if (lr == 0) pw[wave][row] = s;
            }
        __syncthreads();
        if (tid < 64) {
            const float sc = pw[0][tid] + pw[1][tid] + pw[2][tid] + pw[3][tid] + bw[0];
            const float e = __expf(sc);   // no max-subtraction: |sc| <= sum|Ww| (~9), fp32-safe
            es[tid] = e;
            float t2 = e;
#pragma unroll
            for (int o = 32; o > 0; o >>= 1) t2 += __shfl_down(t2, o);
            if (tid == 0) Se[blockIdx.x] = t2;
        }
        __syncthreads();
        float pacc = 0.0f;
#pragma unroll 8
        for (int row = 0; row < 64; ++row) pacc += es[row] * bf2f(HT[row][tid]);
        Zp[(size_t)blockIdx.x * 256 + tid] = pacc;
    }
}

// z = (sum of 32 Zp partials) / (sum of 32 Se); logits = gelu(z@Wc1+bc1)@Wc2 + bc2.
__global__ __launch_bounds__(256) void head_kernel(const float* __restrict__ Zp,
                                                   const float* __restrict__ Se,
                                                   const float* __restrict__ Wc1,
                                                   const float* __restrict__ bc1,
                                                   const float* __restrict__ Wc2,
                                                   const float* __restrict__ bc2,
                                                   float* __restrict__ Out) {
    __shared__ float zs[256];
    __shared__ float hs[128];
    __shared__ float red[4];
    const int seg = blockIdx.x, tid = threadIdx.x;
    float z = 0.0f;
#pragma unroll
    for (int c = 0; c < 32; ++c) z += Zp[((size_t)seg * 32 + c) * 256 + tid];
    float den = 0.0f;
#pragma unroll
    for (int c = 0; c < 32; ++c) den += Se[seg * 32 + c];
    zs[tid] = z / den;
    __syncthreads();
    if (tid < 128) {
        float acc = bc1[tid];
        for (int k = 0; k < 256; k++) acc += zs[k] * Wc1[k * 128 + tid];
        hs[tid] = gelu_exact(acc);
    }
    __syncthreads();
    const int cls = tid >> 7, j = tid & 127;
    float val = hs[j] * Wc2[j * 2 + cls];
#pragma unroll
    for (int o = 32; o > 0; o >>= 1) val += __shfl_down(val, o);
    if ((tid & 63) == 0) red[tid >> 6] = val;
    __syncthreads();
    if (tid < 2) Out[seg * 2 + tid] = red[tid * 2] + red[tid * 2 + 1] + bc2[tid];
}

extern "C" void kernel_launch(void* const* d_in, const int* in_sizes, int n_in,
                              void* d_out, int out_size, void* d_ws, size_t ws_size,
                              hipStream_t stream) {
    const float* x   = (const float*)d_in[0];
    const float* W1  = (const float*)d_in[2];
    const float* b1  = (const float*)d_in[3];
    const float* g1  = (const float*)d_in[4];
    const float* be1 = (const float*)d_in[5];
    const float* W2  = (const float*)d_in[6];
    const float* b2  = (const float*)d_in[7];
    const float* g2  = (const float*)d_in[8];
    const float* be2 = (const float*)d_in[9];
    const float* Wv  = (const float*)d_in[10];
    const float* bv  = (const float*)d_in[11];
    const float* Wu  = (const float*)d_in[12];
    const float* bu  = (const float*)d_in[13];
    const float* Ww  = (const float*)d_in[14];
    const float* bw  = (const float*)d_in[15];
    const float* Wc1 = (const float*)d_in[16];
    const float* bc1 = (const float*)d_in[17];
    const float* Wc2 = (const float*)d_in[18];
    const float* bc2 = (const float*)d_in[19];
    float* out = (float*)d_out;

    char* p = (char*)d_ws;
    unsigned short* W1f  = (unsigned short*)p; p += (size_t)HIDN * DIM * 2;
    unsigned short* W2f  = (unsigned short*)p; p += (size_t)HIDN * HIDN * 2;
    unsigned short* Wvuf = (unsigned short*)p; p += (size_t)HIDN * HIDN * 2;
    float*          Zp   = (float*)p;          p += (size_t)NBLK * HIDN * 4;
    float*          Se   = (float*)p;          p += (size_t)NBLK * 4;

    prep_weights<<<192, 256, 0, stream>>>(W1, W2, Wv, Wu, W1f, W2f, Wvuf);

    fused_mlp_score<<<NBLK, 256, 0, stream>>>(
        x, W1f, W2f, Wvuf,
        b1, g1, be1, b2, g2, be2,
        bv, bu, Ww, bw, Zp, Se);

    head_kernel<<<NSEG, 256, 0, stream>>>(Zp, Se, Wc1, bc1, Wc2, bc2, out);
}